// Round 3
// baseline (182.963 us; speedup 1.0000x reference)
//
#include <hip/hip_runtime.h>
#include <stdint.h>

#define OUT_F   4096
#define IN_F    11008
#define BATCH   64
#define NSUP    43                  // super-blocks per row
#define SB_ROW  344                 // sub-blocks per row
#define IPR     5504                // int32 elements per weight row
#define NKS     12                  // K-splits -> 64 x 12 = 768 blocks = 3/CU exactly
#define PART_ELEMS ((size_t)NKS * BATCH * OUT_F)
#define WS_FULL    (PART_ELEMS * 4)

typedef __attribute__((ext_vector_type(8))) short  short8;
typedef __attribute__((ext_vector_type(4))) float  floatx4;
typedef __attribute__((ext_vector_type(4))) int    intx4;

template<int N> struct IC { static constexpr int value = N; };

__device__ __forceinline__ unsigned pack_bf16(float f0, float f1) {
    return __builtin_amdgcn_perm(__float_as_uint(f1), __float_as_uint(f0), 0x07060302u);
}

__global__ __launch_bounds__(256) void init_out_kernel(const float* __restrict__ bias,
                                                       float* __restrict__ out) {
    int i = blockIdx.x * 256 + threadIdx.x;
    out[i] = bias[i & (OUT_F - 1)];
}

__global__ __launch_bounds__(256) void reduce_kernel(const float* __restrict__ part,
                                                     const float* __restrict__ bias,
                                                     float* __restrict__ out) {
    const int i = blockIdx.x * 256 + threadIdx.x;
    float s = bias[i & (OUT_F - 1)];
    #pragma unroll
    for (int k = 0; k < NKS; ++k) s += part[(size_t)k * (BATCH * OUT_F) + i];
    out[i] = s;
}

// block = 64 out-features x 64 batch rows. xprep is FUSED: each block repacks
// its own 64KB x-slice per super (x is 2.8MB, L3-resident) into MFMA A-fragment
// order in LDS. Weight loads issue first (HBM latency leads); barriers are raw
// s_barrier + lgkmcnt(0) so scale/d loads are never force-drained.
template<bool USE_PART>
__global__ __launch_bounds__(256, 3) void qlin_main(
    const float* __restrict__ x,
    const int*   __restrict__ packed,
    const float* __restrict__ dd,
    const float* __restrict__ dmn_g,
    const int*   __restrict__ scales,
    const int*   __restrict__ mins,
    float*       __restrict__ part,
    float*       __restrict__ out)
{
    __shared__ intx4 xfs[2048];     // 32KB  [mt*512 + st*64 + l]

    const int nb  = blockIdx.x & 63;
    const int ks  = blockIdx.x >> 6;          // 0..11
    const int tid = threadIdx.x;
    const int w   = tid >> 6;
    const int l   = tid & 63;
    const int lo  = l & 15, hi = l >> 4;

    const int o    = nb * 64 + w * 16 + lo;   // lane's out-feature
    const int sup0 = ks < 7 ? 4 * ks : 28 + 3 * (ks - 7);
    const int nsup = ks < 7 ? 4 : 3;

    floatx4 acc[4];
    #pragma unroll
    for (int mt = 0; mt < 4; ++mt) acc[mt] = (floatx4)0.0f;

    const int*   bp0 = packed + o * IPR + sup0 * 128 + hi * 4;
    const int*   scp = scales + o * SB_ROW + sup0 * 8;
    const int*   mnp = mins   + o * SB_ROW + sup0 * 8;
    const float* dp  = dd     + o * NSUP + sup0;
    const float* dmp = dmn_g  + o * NSUP + sup0;

    // per-thread x source offsets for the 8 LDS slots this thread fills.
    // slot n = i*256+tid:  mt=n>>9, st=(n>>6)&7, l2=n&63
    // x elem = x[(mt*16 + (l2&15)) * IN_F + sup*256 + st*32 + (l2>>4)*8 .. +8)
    int xoff[8];
    #pragma unroll
    for (int i = 0; i < 8; ++i) {
        const int n  = i * 256 + tid;
        const int mt = n >> 9;
        const int st2 = (n >> 6) & 7;
        const int l2 = n & 63;
        xoff[i] = (mt * 16 + (l2 & 15)) * IN_F + st2 * 32 + (l2 >> 4) * 8;
    }

    auto run = [&](auto nsc) {
        constexpr int NS = decltype(nsc)::value;
        #pragma unroll
        for (int s = 0; s < NS; ++s) {
            const int sup = sup0 + s;

            // ---- weights first: longest-latency HBM stream ----
            intx4 br[8];
            #pragma unroll
            for (int st = 0; st < 8; ++st)
                br[st] = __builtin_nontemporal_load((const intx4*)(bp0 + s * 128 + st * 16));
            const intx4 s0v = *(const intx4*)(scp + s * 8);
            const intx4 s1v = *(const intx4*)(scp + s * 8 + 4);
            const intx4 m0v = *(const intx4*)(mnp + s * 8);
            const intx4 m1v = *(const intx4*)(mnp + s * 8 + 4);
            const float dv  = dp[s];
            const float dmv = dmp[s];

            // ---- x load + pack (L3-hot; waits are counted, weights fly on) ----
            intx4 xt[8];
            #pragma unroll
            for (int i = 0; i < 8; ++i) {
                const float* src = x + xoff[i] + sup * 256;
                floatx4 a0 = *(const floatx4*)src;
                floatx4 a1 = *(const floatx4*)(src + 4);
                xt[i].x = pack_bf16(a0.x, a0.y);
                xt[i].y = pack_bf16(a0.z, a0.w);
                xt[i].z = pack_bf16(a1.x, a1.y);
                xt[i].w = pack_bf16(a1.z, a1.w);
            }

            // ---- commit to LDS ----
            if (s > 0) __builtin_amdgcn_s_barrier();   // prev super's readers done
            #pragma unroll
            for (int i = 0; i < 8; ++i)
                xfs[i * 256 + tid] = xt[i];
            asm volatile("s_waitcnt lgkmcnt(0)" ::: "memory");
            __builtin_amdgcn_sched_barrier(0);
            __builtin_amdgcn_s_barrier();              // xfs visible to all waves

            // ---- 8 K-steps: dequant + MFMA ----
            const float A945 = dv * (1.0f / 945.0f);
            const float A63  = dv * (1.0f / 63.0f);
            #pragma unroll
            for (int st = 0; st < 8; ++st) {
                const int scv = (st < 4) ? s0v[st & 3] : s1v[st & 3];
                const int mnv = (st < 4) ? m0v[st & 3] : m1v[st & 3];
                const float A = A945 * (float)scv;
                const float B = fmaf(A63, (float)mnv, dmv);
                const int v0 = br[st].x, v1 = br[st].y, v2 = br[st].z, v3 = br[st].w;
                union { intx4 i; short8 s8; } uw;
                uw.i.x = pack_bf16(fmaf((float)(v0 & 15), A, B), fmaf((float)(v0 >> 4), A, B));
                uw.i.y = pack_bf16(fmaf((float)(v1 & 15), A, B), fmaf((float)(v1 >> 4), A, B));
                uw.i.z = pack_bf16(fmaf((float)(v2 & 15), A, B), fmaf((float)(v2 >> 4), A, B));
                uw.i.w = pack_bf16(fmaf((float)(v3 & 15), A, B), fmaf((float)(v3 >> 4), A, B));

                union { intx4 i; short8 s8; } u0, u1, u2, u3;
                u0.i = xfs[0 * 512 + st * 64 + l];
                u1.i = xfs[1 * 512 + st * 64 + l];
                u2.i = xfs[2 * 512 + st * 64 + l];
                u3.i = xfs[3 * 512 + st * 64 + l];
                acc[0] = __builtin_amdgcn_mfma_f32_16x16x32_bf16(u0.s8, uw.s8, acc[0], 0, 0, 0);
                acc[1] = __builtin_amdgcn_mfma_f32_16x16x32_bf16(u1.s8, uw.s8, acc[1], 0, 0, 0);
                acc[2] = __builtin_amdgcn_mfma_f32_16x16x32_bf16(u2.s8, uw.s8, acc[2], 0, 0, 0);
                acc[3] = __builtin_amdgcn_mfma_f32_16x16x32_bf16(u3.s8, uw.s8, acc[3], 0, 0, 0);
            }
        }
    };
    if (nsup == 4) run(IC<4>{});
    else           run(IC<3>{});

    // ---- epilogue: D col = lane&15 = n (out-feature o), row = hi*4+rr = m ----
    if (USE_PART) {
        float* pbase = part + (size_t)ks * (BATCH * OUT_F) + o;
        #pragma unroll
        for (int mt = 0; mt < 4; ++mt) {
            #pragma unroll
            for (int rr = 0; rr < 4; ++rr)
                pbase[(mt * 16 + hi * 4 + rr) * OUT_F] = acc[mt][rr];
        }
    } else {
        #pragma unroll
        for (int mt = 0; mt < 4; ++mt) {
            #pragma unroll
            for (int rr = 0; rr < 4; ++rr)
                atomicAdd(out + (mt * 16 + hi * 4 + rr) * OUT_F + o, acc[mt][rr]);
        }
    }
}

extern "C" void kernel_launch(void* const* d_in, const int* in_sizes, int n_in,
                              void* d_out, int out_size, void* d_ws, size_t ws_size,
                              hipStream_t stream) {
    (void)in_sizes; (void)n_in; (void)out_size;
    const float* x      = (const float*)d_in[0];
    const int*   packed = (const int*)d_in[1];
    const float* d      = (const float*)d_in[2];
    const float* dmin   = (const float*)d_in[3];
    const int*   scales = (const int*)d_in[4];
    const int*   mins   = (const int*)d_in[5];
    const float* bias   = (const float*)d_in[6];
    float* out = (float*)d_out;

    const bool has_part = ws_size >= (size_t)WS_FULL;
    float* part = (float*)d_ws;

    if (has_part) {
        qlin_main<true><<<64 * NKS, 256, 0, stream>>>(
            x, packed, d, dmin, scales, mins, part, out);
        reduce_kernel<<<(BATCH * OUT_F) / 256, 256, 0, stream>>>(part, bias, out);
    } else {
        init_out_kernel<<<(BATCH * OUT_F) / 256, 256, 0, stream>>>(bias, out);
        qlin_main<false><<<64 * NKS, 256, 0, stream>>>(
            x, packed, d, dmin, scales, mins, part, out);
    }
}

// Round 4
// 166.067 us; speedup vs baseline: 1.1017x; 1.1017x over previous
//
#include <hip/hip_runtime.h>
#include <stdint.h>

#define OUT_F   4096
#define IN_F    11008
#define BATCH   64
#define NSUP    43                  // super-blocks per row
#define SB_ROW  344                 // sub-blocks per row
#define IPR     5504                // int32 elements per weight row
#define NKS     8                   // K-splits -> 64 x 8 = 512 blocks = 2/CU exactly
#define XP_BYTES   (4 * 344 * 64 * 16)              // 1,409,024 B
#define PART_ELEMS ((size_t)NKS * BATCH * OUT_F)
#define WS_FULL    (XP_BYTES + PART_ELEMS * 4)

typedef __attribute__((ext_vector_type(8))) short  short8;
typedef __attribute__((ext_vector_type(4))) float  floatx4;
typedef __attribute__((ext_vector_type(4))) int    intx4;

template<int N> struct IC { static constexpr int value = N; };

__device__ __forceinline__ unsigned pack_bf16(float f0, float f1) {
    return __builtin_amdgcn_perm(__float_as_uint(f1), __float_as_uint(f0), 0x07060302u);
}

// global -> LDS direct copy, 16B per lane, dest = wave-uniform base + lane*16
__device__ __forceinline__ void glds16(const void* g, void* s) {
    __builtin_amdgcn_global_load_lds(
        (const __attribute__((address_space(1))) uint32_t*)g,
        (__attribute__((address_space(3))) uint32_t*)s,
        16, 0, 0);
}

__device__ __forceinline__ void group_fence(void) {
    asm volatile("" ::: "memory");              // compiler fence: pin issue groups
    __builtin_amdgcn_sched_barrier(0);          // machine-scheduler fence
}

// ---- pre-pack x into MFMA A-fragment order: xp[(mt*344 + ksb)*64 + l] ----
__global__ __launch_bounds__(256) void xprep_kernel(const float* __restrict__ x,
                                                    intx4* __restrict__ xp) {
    const int ksb = blockIdx.x;            // 0..343
    const int mt  = threadIdx.x >> 6;
    const int l   = threadIdx.x & 63;
    const int lo  = l & 15, hi = l >> 4;
    const float* src = x + (mt * 16 + lo) * IN_F + ksb * 32 + hi * 8;
    floatx4 a0 = *(const floatx4*)src;
    floatx4 a1 = *(const floatx4*)(src + 4);
    intx4 r;
    r.x = pack_bf16(a0.x, a0.y);
    r.y = pack_bf16(a0.z, a0.w);
    r.z = pack_bf16(a1.x, a1.y);
    r.w = pack_bf16(a1.z, a1.w);
    xp[(mt * 344 + ksb) * 64 + l] = r;
}

__global__ __launch_bounds__(256) void init_out_kernel(const float* __restrict__ bias,
                                                       float* __restrict__ out) {
    int i = blockIdx.x * 256 + threadIdx.x;
    out[i] = bias[i & (OUT_F - 1)];
}

__global__ __launch_bounds__(256) void reduce_kernel(const float* __restrict__ part,
                                                     const float* __restrict__ bias,
                                                     float* __restrict__ out) {
    const int i = blockIdx.x * 256 + threadIdx.x;
    float s = bias[i & (OUT_F - 1)];
    #pragma unroll
    for (int k = 0; k < NKS; ++k) s += part[(size_t)k * (BATCH * OUT_F) + i];
    out[i] = s;
}

// block = 64 out-features x 64 batch rows, NKS=8 K-splits, 2 blocks/CU.
// Counted-vmcnt pipeline: per-super issue group = [8 weights + 6 scales + 8 glds]
// = 22 VMEM ops; two groups permanently in flight; each super waits
// s_waitcnt vmcnt(22) (retire exactly one group, next keeps flying over
// ~2 compute phases). Raw s_barrier never drains vmcnt. x double-buffered.
template<bool USE_PART>
__global__ __launch_bounds__(256, 2) void qlin_main(
    const intx4* __restrict__ xp,
    const int*   __restrict__ packed,
    const float* __restrict__ dd,
    const float* __restrict__ dmn_g,
    const int*   __restrict__ scales,
    const int*   __restrict__ mins,
    float*       __restrict__ part,
    float*       __restrict__ out)
{
    __shared__ intx4 xfs[2][2048];   // 2 x 32KB double-buffered x tile

    const int nb  = blockIdx.x & 63;
    const int ks  = blockIdx.x >> 6;          // 0..7
    const int tid = threadIdx.x;
    const int w   = tid >> 6;
    const int l   = tid & 63;
    const int lo  = l & 15, hi = l >> 4;
    const int wq  = tid & 192;                // w*64: wave-uniform LDS slice

    const int o    = nb * 64 + w * 16 + lo;   // lane's out-feature
    const int sup0 = ks < 3 ? 6 * ks : 18 + 5 * (ks - 3);
    const int nsup = ks < 3 ? 6 : 5;

    floatx4 acc[4];
    #pragma unroll
    for (int mt = 0; mt < 4; ++mt) acc[mt] = (floatx4)0.0f;

    const int*   bp0 = packed + o * IPR + sup0 * 128 + hi * 4;
    const int*   scp = scales + o * SB_ROW + sup0 * 8;
    const int*   mnp = mins   + o * SB_ROW + sup0 * 8;
    const float* dp  = dd     + o * NSUP + sup0;
    const float* dmp = dmn_g  + o * NSUP + sup0;

    // 8 glds for one super's x tile into buffer `buf`
    auto stage_x = [&](int sup_abs, int buf) {
        #pragma unroll
        for (int i = 0; i < 8; ++i) {
            const intx4* src = xp + (i >> 1) * 22016 + sup_abs * 512 + (i & 1) * 256 + tid;
            glds16((const void*)src, (void*)&xfs[buf][i * 256 + wq]);
        }
    };

    auto run = [&](auto nsc) {
        constexpr int NS = decltype(nsc)::value;
        intx4 br[NS][8];
        intx4 s0[NS], s1[NS], m0[NS], m1[NS];
        float dv[NS], dmv[NS];

        // 14 register-dest loads for super s (weights + dequant scalars)
        auto issue_w = [&](int s) {
            #pragma unroll
            for (int st = 0; st < 8; ++st)
                br[s][st] = __builtin_nontemporal_load((const intx4*)(bp0 + s * 128 + st * 16));
            s0[s]  = *(const intx4*)(scp + s * 8);
            s1[s]  = *(const intx4*)(scp + s * 8 + 4);
            m0[s]  = *(const intx4*)(mnp + s * 8);
            m1[s]  = *(const intx4*)(mnp + s * 8 + 4);
            dv[s]  = dp[s];
            dmv[s] = dmp[s];
        };

        // dequant + 8 K-steps of MFMA from buffer buf (no VMEM inside)
        auto compute_sup = [&](int s, int buf) {
            const float A945 = dv[s] * (1.0f / 945.0f);
            const float A63  = dv[s] * (1.0f / 63.0f);
            #pragma unroll
            for (int st = 0; st < 8; ++st) {
                const int scv = (st < 4) ? s0[s][st & 3] : s1[s][st & 3];
                const int mnv = (st < 4) ? m0[s][st & 3] : m1[s][st & 3];
                const float A = A945 * (float)scv;
                const float B = fmaf(A63, (float)mnv, dmv[s]);
                const int v0 = br[s][st].x, v1 = br[s][st].y;
                const int v2 = br[s][st].z, v3 = br[s][st].w;
                union { intx4 i; short8 s8; } uw;
                uw.i.x = pack_bf16(fmaf((float)(v0 & 15), A, B), fmaf((float)(v0 >> 4), A, B));
                uw.i.y = pack_bf16(fmaf((float)(v1 & 15), A, B), fmaf((float)(v1 >> 4), A, B));
                uw.i.z = pack_bf16(fmaf((float)(v2 & 15), A, B), fmaf((float)(v2 >> 4), A, B));
                uw.i.w = pack_bf16(fmaf((float)(v3 & 15), A, B), fmaf((float)(v3 >> 4), A, B));

                union { intx4 i; short8 s8; } u0, u1, u2, u3;
                u0.i = xfs[buf][0 * 512 + st * 64 + l];
                u1.i = xfs[buf][1 * 512 + st * 64 + l];
                u2.i = xfs[buf][2 * 512 + st * 64 + l];
                u3.i = xfs[buf][3 * 512 + st * 64 + l];
                acc[0] = __builtin_amdgcn_mfma_f32_16x16x32_bf16(u0.s8, uw.s8, acc[0], 0, 0, 0);
                acc[1] = __builtin_amdgcn_mfma_f32_16x16x32_bf16(u1.s8, uw.s8, acc[1], 0, 0, 0);
                acc[2] = __builtin_amdgcn_mfma_f32_16x16x32_bf16(u2.s8, uw.s8, acc[2], 0, 0, 0);
                acc[3] = __builtin_amdgcn_mfma_f32_16x16x32_bf16(u3.s8, uw.s8, acc[3], 0, 0, 0);
            }
        };

        // ---- prologue: two super-groups in flight, hard fence between ----
        issue_w(0); stage_x(sup0 + 0, 0);
        group_fence();
        issue_w(1); stage_x(sup0 + 1, 1);
        group_fence();

        #pragma unroll
        for (int s = 0; s < NS; ++s) {
            // retire exactly group s; group s+1 (22 ops) stays in flight
            if (s + 1 < NS) asm volatile("s_waitcnt vmcnt(22)" ::: "memory");
            else            asm volatile("s_waitcnt vmcnt(0)"  ::: "memory");
            __builtin_amdgcn_sched_barrier(0);
            __builtin_amdgcn_s_barrier();           // group-s glds visible to all waves

            if (s + 2 < NS) issue_w(s + 2);         // regs: flies over compute s, s+1

            compute_sup(s, s & 1);

            if (s + 2 < NS) {
                __builtin_amdgcn_s_barrier();       // all waves done reading buf s&1
                stage_x(sup0 + s + 2, s & 1);       // refill freed buffer
                group_fence();
            }
        }
    };
    if (nsup == 6) run(IC<6>{});
    else           run(IC<5>{});

    // ---- epilogue: D col = lane&15 = n (out-feature o), row = hi*4+rr = m ----
    if (USE_PART) {
        float* pbase = part + (size_t)ks * (BATCH * OUT_F) + o;
        #pragma unroll
        for (int mt = 0; mt < 4; ++mt) {
            #pragma unroll
            for (int rr = 0; rr < 4; ++rr)
                pbase[(mt * 16 + hi * 4 + rr) * OUT_F] = acc[mt][rr];
        }
    } else {
        #pragma unroll
        for (int mt = 0; mt < 4; ++mt) {
            #pragma unroll
            for (int rr = 0; rr < 4; ++rr)
                atomicAdd(out + (mt * 16 + hi * 4 + rr) * OUT_F + o, acc[mt][rr]);
        }
    }
}

extern "C" void kernel_launch(void* const* d_in, const int* in_sizes, int n_in,
                              void* d_out, int out_size, void* d_ws, size_t ws_size,
                              hipStream_t stream) {
    (void)in_sizes; (void)n_in; (void)out_size;
    const float* x      = (const float*)d_in[0];
    const int*   packed = (const int*)d_in[1];
    const float* d      = (const float*)d_in[2];
    const float* dmin   = (const float*)d_in[3];
    const int*   scales = (const int*)d_in[4];
    const int*   mins   = (const int*)d_in[5];
    const float* bias   = (const float*)d_in[6];
    float* out = (float*)d_out;

    const bool has_part = ws_size >= (size_t)WS_FULL;
    intx4* xp   = (intx4*)d_ws;
    float* part = (float*)((char*)d_ws + XP_BYTES);

    xprep_kernel<<<344, 256, 0, stream>>>(x, xp);

    if (has_part) {
        qlin_main<true><<<64 * NKS, 256, 0, stream>>>(
            xp, packed, d, dmin, scales, mins, part, out);
        reduce_kernel<<<(BATCH * OUT_F) / 256, 256, 0, stream>>>(part, bias, out);
    } else {
        init_out_kernel<<<(BATCH * OUT_F) / 256, 256, 0, stream>>>(bias, out);
        qlin_main<false><<<64 * NKS, 256, 0, stream>>>(
            xp, packed, d, dmin, scales, mins, part, out);
    }
}